// Round 2
// baseline (56.310 us; speedup 1.0000x reference)
//
#include <hip/hip_runtime.h>
#include <cstdint>
#include <cmath>

#define EPS_F 1e-8f

constexpr int B = 8, H = 8, CELLS = 8192, W = 256;
constexpr int W4 = 64;            // float4 per W-row
constexpr int CBLK = 256;         // cells per block in kernel1
constexpr int NBLK = CELLS / CBLK; // 32 score-blocks per (b) row-group

// ws layout (floats):
//   [0, 32768)        kqm2 [B][W4][16 float4]: per (b,w4) f4 0..7 = kq4[h], 8..15 = m2_4[h]
//   [32768, 32832)    kn   [B][H]
//   [32832, 36928)    part [B][H][NBLK][2]  (block max, block sumexp)
constexpr size_t OFF_KN   = 32768;
constexpr size_t OFF_PART = 32832;

// ---------------------------------------------------------------------------
// Kernel 0: per (b,h): kq = k*m^2, m2 = m^2 (interleaved per-w4 layout),
//           kn = ||k*m||.  grid = 64 blocks x 256 threads (w).
// ---------------------------------------------------------------------------
__global__ __launch_bounds__(256) void ca_prep(
    const float* __restrict__ keys, const float* __restrict__ mask,
    float* __restrict__ ws)
{
    const int bh = blockIdx.x;        // b*8 + h
    const int b = bh >> 3, h = bh & 7;
    const int t = threadIdx.x;        // w
    float k = keys[bh * W + t];
    float m = mask[bh * W + t];       // MASK_MIN = 0 -> mask unchanged
    float m2 = m * m;
    const int w4 = t >> 2, e = t & 3;
    ws[(((size_t)b * W4 + w4) * 16 + h) * 4 + e]     = k * m2;
    ws[(((size_t)b * W4 + w4) * 16 + 8 + h) * 4 + e] = m2;

    float km = k * m;
    float v = km * km;
#pragma unroll
    for (int s = 32; s; s >>= 1) v += __shfl_xor(v, s, 64);
    __shared__ float red[4];
    const int lane = t & 63, wv = t >> 6;
    if (lane == 0) red[wv] = v;
    __syncthreads();
    if (t == 0) ws[OFF_KN + bh] = sqrtf((red[0] + red[1]) + (red[2] + red[3]));
}

// ---------------------------------------------------------------------------
// Kernel 1: thread-per-cell, all 8 heads in registers. No LDS on hot path.
// grid = (NBLK, B), block = 256. Also writes per-(h,block) softmax partials.
// ---------------------------------------------------------------------------
__global__ __launch_bounds__(256) void ca_scores(
    const float4* __restrict__ mem4,   // [B*CELLS][W4]
    const float* __restrict__ ws,
    const float* __restrict__ betas,   // [B*H]
    float* __restrict__ out,           // [B*H][CELLS]
    float* __restrict__ part)
{
    const int b = blockIdx.y, blk = blockIdx.x, t = threadIdx.x;
    const int c = blk * CBLK + t;
    const float4* __restrict__ mrow = mem4 + ((size_t)b * CELLS + c) * W4;
    const float4* __restrict__ kb = (const float4*)ws + (size_t)b * W4 * 16;

    float2 dot[H], nr[H];
#pragma unroll
    for (int h = 0; h < H; ++h) {
        dot[h] = make_float2(0.f, 0.f);
        nr[h]  = make_float2(0.f, 0.f);
    }

    for (int g = 0; g < 8; ++g) {          // 8 groups of 8 float4 = 128B/group
        float4 mv[8];
#pragma unroll
        for (int j = 0; j < 8; ++j) mv[j] = mrow[g * 8 + j];
#pragma unroll
        for (int j = 0; j < 8; ++j) {
            const float4* __restrict__ kk = kb + (g * 8 + j) * 16; // uniform -> s_load
            float4 a = mv[j];
            float4 s = make_float4(a.x * a.x, a.y * a.y, a.z * a.z, a.w * a.w);
#pragma unroll
            for (int h = 0; h < H; ++h) {
                float4 kq = kk[h];
                float4 q  = kk[8 + h];
                dot[h].x = fmaf(a.y, kq.y, fmaf(a.x, kq.x, dot[h].x));
                dot[h].y = fmaf(a.w, kq.w, fmaf(a.z, kq.z, dot[h].y));
                nr[h].x  = fmaf(s.y, q.y,  fmaf(s.x, q.x,  nr[h].x));
                nr[h].y  = fmaf(s.w, q.w,  fmaf(s.z, q.z,  nr[h].y));
            }
        }
    }

    // epilogue: score + store
    float score[H];
#pragma unroll
    for (int h = 0; h < H; ++h) {
        float d    = dot[h].x + dot[h].y;
        float n    = sqrtf(nr[h].x + nr[h].y);
        float knh  = ws[OFF_KN + b * H + h];     // uniform
        float beta = betas[b * H + h];           // uniform
        score[h] = d * beta / (knh * n + EPS_F);
        out[((size_t)(b * H + h)) * CELLS + c] = score[h];
    }

    // fused softmax partials: per h, block max + block sum(exp(x - bmax))
    __shared__ float sred[H][4];
    __shared__ float sbmax[H];
    const int lane = t & 63, wv = t >> 6;
#pragma unroll
    for (int h = 0; h < H; ++h) {
        float v = score[h];
#pragma unroll
        for (int s = 32; s; s >>= 1) v = fmaxf(v, __shfl_xor(v, s, 64));
        if (lane == 0) sred[h][wv] = v;
    }
    __syncthreads();
    if (t < H) sbmax[t] = fmaxf(fmaxf(sred[t][0], sred[t][1]),
                                fmaxf(sred[t][2], sred[t][3]));
    __syncthreads();
#pragma unroll
    for (int h = 0; h < H; ++h) {
        float v = expf(score[h] - sbmax[h]);
#pragma unroll
        for (int s = 32; s; s >>= 1) v += __shfl_xor(v, s, 64);
        if (lane == 0) sred[h][wv] = v;
    }
    __syncthreads();
    if (t < H) {
        float s4 = (sred[t][0] + sred[t][1]) + (sred[t][2] + sred[t][3]);
        size_t pi = (((size_t)(b * H + t)) * NBLK + blk) * 2;
        part[pi]     = sbmax[t];
        part[pi + 1] = s4;
    }
}

// ---------------------------------------------------------------------------
// Kernel 2: combine per-row partials (redundant per block, uniform scalar
// reads) and normalize. grid = 128 blocks (2 per row), block = 256.
// ---------------------------------------------------------------------------
__global__ __launch_bounds__(256) void ca_norm(
    float* __restrict__ out, const float* __restrict__ part)
{
    const int row  = blockIdx.x >> 1;   // 0..63 = b*H + h
    const int half = blockIdx.x & 1;
    const int t = threadIdx.x;

    const float2* __restrict__ pp = (const float2*)(part + (size_t)row * (NBLK * 2));
    float gm = -INFINITY;
#pragma unroll
    for (int i = 0; i < NBLK; ++i) gm = fmaxf(gm, pp[i].x);
    float gs = 0.f;
#pragma unroll
    for (int i = 0; i < NBLK; ++i) gs += pp[i].y * expf(pp[i].x - gm);
    float inv = 1.0f / gs;

    float4* p = (float4*)(out + (size_t)row * CELLS) + half * 1024;
#pragma unroll
    for (int i = 0; i < 4; ++i) {
        float4 v = p[t + i * 256];
        v.x = expf(v.x - gm) * inv;
        v.y = expf(v.y - gm) * inv;
        v.z = expf(v.z - gm) * inv;
        v.w = expf(v.w - gm) * inv;
        p[t + i * 256] = v;
    }
}

// ---------------------------------------------------------------------------
extern "C" void kernel_launch(void* const* d_in, const int* in_sizes, int n_in,
                              void* d_out, int out_size, void* d_ws, size_t ws_size,
                              hipStream_t stream) {
    (void)in_sizes; (void)n_in; (void)out_size; (void)ws_size;
    const float* memory = (const float*)d_in[0];
    const float* keys   = (const float*)d_in[1];
    const float* betas  = (const float*)d_in[2];
    const float* mask   = (const float*)d_in[3];
    float* out = (float*)d_out;
    float* ws  = (float*)d_ws;

    ca_prep<<<B * H, 256, 0, stream>>>(keys, mask, ws);
    dim3 g1(NBLK, B);
    ca_scores<<<g1, 256, 0, stream>>>((const float4*)memory, ws, betas, out,
                                      ws + OFF_PART);
    ca_norm<<<2 * B * H, 256, 0, stream>>>(out, ws + OFF_PART);
}

// Round 3
// 50.467 us; speedup vs baseline: 1.1158x; 1.1158x over previous
//
#include <hip/hip_runtime.h>
#include <cstdint>
#include <cmath>

#define EPS_F 1e-8f

constexpr int B = 8, H = 8, CELLS = 8192, W = 256;
constexpr int W4 = 64;             // float4 per W-row
constexpr int CPB = 64;            // cells per block in kernel1
constexpr int NBLK = CELLS / CPB;  // 128 score-blocks per (b,h) row

// ws layout (floats):
//   [0, 32768)        kqm2 [B][W4][16 float4]: f4 0..7 = kq4[h], 8..15 = m2_4[h]
//   [32768, 32832)    kn   [B][H]
//   [32832, +16384)   part [B][H][NBLK][2]  (block max, block sumexp)
constexpr size_t OFF_KN   = 32768;
constexpr size_t OFF_PART = 32832;

// ---------------------------------------------------------------------------
// Kernel 0: per (b,h): kq = k*m^2, m2 = m^2 (per-w4 interleaved), kn = ||k*m||
// ---------------------------------------------------------------------------
__global__ __launch_bounds__(256) void ca_prep(
    const float* __restrict__ keys, const float* __restrict__ mask,
    float* __restrict__ ws)
{
    const int bh = blockIdx.x;        // b*8 + h
    const int b = bh >> 3, h = bh & 7;
    const int t = threadIdx.x;        // w
    float k = keys[bh * W + t];
    float m = mask[bh * W + t];       // MASK_MIN = 0 -> mask unchanged
    float m2 = m * m;
    const int w4 = t >> 2, e = t & 3;
    ws[(((size_t)b * W4 + w4) * 16 + h) * 4 + e]     = k * m2;
    ws[(((size_t)b * W4 + w4) * 16 + 8 + h) * 4 + e] = m2;

    float km = k * m;
    float v = km * km;
#pragma unroll
    for (int s = 32; s; s >>= 1) v += __shfl_xor(v, s, 64);
    __shared__ float red[4];
    const int lane = t & 63, wv = t >> 6;
    if (lane == 0) red[wv] = v;
    __syncthreads();
    if (t == 0) ws[OFF_KN + bh] = sqrtf((red[0] + red[1]) + (red[2] + red[3]));
}

// ---------------------------------------------------------------------------
// Kernel 1: 64 cells/block, 4 waves; wave wv owns W-quarter wv of every cell.
// grid = (NBLK, B) = (128, 8) -> 1024 blocks -> 16 waves/CU.
// ---------------------------------------------------------------------------
__global__ __launch_bounds__(256, 4) void ca_scores(
    const float4* __restrict__ mem4,   // [B*CELLS][W4]
    const float* __restrict__ ws,
    const float* __restrict__ betas,   // [B*H]
    float* __restrict__ out,           // [B*H][CELLS]
    float* __restrict__ part)
{
    const int b = blockIdx.y, blk = blockIdx.x, t = threadIdx.x;
    const int lane = t & 63;
    const int wvu  = __builtin_amdgcn_readfirstlane(t >> 6);  // wave-uniform
    const int c0   = blk * CPB;
    const int cell = c0 + lane;

    const float4* __restrict__ mrow = mem4 + ((size_t)b * CELLS + cell) * W4 + wvu * 16;
    const float4* __restrict__ kb   = (const float4*)ws + ((size_t)b * W4 + wvu * 16) * 16;

    float dot[H], nr[H];
#pragma unroll
    for (int h = 0; h < H; ++h) { dot[h] = 0.f; nr[h] = 0.f; }

#pragma unroll
    for (int g = 0; g < 2; ++g) {          // 2 batches of 8 float4 (MLP=8)
        float4 mv[8];
#pragma unroll
        for (int j = 0; j < 8; ++j) mv[j] = mrow[g * 8 + j];
#pragma unroll
        for (int j = 0; j < 8; ++j) {
            const float4* __restrict__ kk = kb + (g * 8 + j) * 16;  // wave-uniform -> s_load
            float4 a = mv[j];
            float4 s = make_float4(a.x * a.x, a.y * a.y, a.z * a.z, a.w * a.w);
#pragma unroll
            for (int h = 0; h < H; ++h) {
                float4 kq = kk[h];
                float4 q  = kk[8 + h];
                dot[h] = fmaf(a.w, kq.w, fmaf(a.z, kq.z, fmaf(a.y, kq.y, fmaf(a.x, kq.x, dot[h]))));
                nr[h]  = fmaf(s.w, q.w,  fmaf(s.z, q.z,  fmaf(s.y, q.y,  fmaf(s.x, q.x,  nr[h]))));
            }
        }
    }

    // cross-wave (quarter) reduction through padded LDS
    __shared__ float lds[4][CPB][17];      // stride 17 -> 2-way bank alias (free)
#pragma unroll
    for (int h = 0; h < H; ++h) {
        lds[wvu][lane][h]     = dot[h];
        lds[wvu][lane][8 + h] = nr[h];
    }
    __syncthreads();

    // wave wvu finalizes heads h0 = 2*wvu, h0+1 for all 64 cells (lane = cell)
    const int h0 = 2 * wvu, h1 = h0 + 1;
    float d0 = 0.f, n0 = 0.f, d1 = 0.f, n1 = 0.f;
#pragma unroll
    for (int w = 0; w < 4; ++w) {
        d0 += lds[w][lane][h0];     n0 += lds[w][lane][8 + h0];
        d1 += lds[w][lane][h1];     n1 += lds[w][lane][8 + h1];
    }
    const float kn0 = ws[OFF_KN + b * H + h0], kn1 = ws[OFF_KN + b * H + h1];
    const float be0 = betas[b * H + h0],       be1 = betas[b * H + h1];
    float s0 = d0 * be0 / (kn0 * sqrtf(n0) + EPS_F);
    float s1 = d1 * be1 / (kn1 * sqrtf(n1) + EPS_F);

    out[((size_t)(b * H + h0)) * CELLS + cell] = s0;
    out[((size_t)(b * H + h1)) * CELLS + cell] = s1;

    // softmax partials: each wave fully owns its 2 heads over the 64 cells
    float m0 = s0, m1 = s1;
#pragma unroll
    for (int s = 32; s; s >>= 1) {
        m0 = fmaxf(m0, __shfl_xor(m0, s, 64));
        m1 = fmaxf(m1, __shfl_xor(m1, s, 64));
    }
    float e0 = expf(s0 - m0), e1 = expf(s1 - m1);
#pragma unroll
    for (int s = 32; s; s >>= 1) {
        e0 += __shfl_xor(e0, s, 64);
        e1 += __shfl_xor(e1, s, 64);
    }
    if (lane == 0) {
        size_t p0 = (((size_t)(b * H + h0)) * NBLK + blk) * 2;
        size_t p1 = (((size_t)(b * H + h1)) * NBLK + blk) * 2;
        part[p0] = m0; part[p0 + 1] = e0;
        part[p1] = m1; part[p1 + 1] = e1;
    }
}

// ---------------------------------------------------------------------------
// Kernel 2: combine per-row partials (redundant, uniform scalar reads) and
// normalize. grid = 128 blocks (2 per row), block = 256.
// ---------------------------------------------------------------------------
__global__ __launch_bounds__(256) void ca_norm(
    float* __restrict__ out, const float* __restrict__ part)
{
    const int row  = blockIdx.x >> 1;   // 0..63 = b*H + h
    const int half = blockIdx.x & 1;
    const int t = threadIdx.x;

    const float2* __restrict__ pp = (const float2*)(part + (size_t)row * (NBLK * 2));
    float gm = -INFINITY;
#pragma unroll 8
    for (int i = 0; i < NBLK; ++i) gm = fmaxf(gm, pp[i].x);
    float gs0 = 0.f, gs1 = 0.f, gs2 = 0.f, gs3 = 0.f;
#pragma unroll 8
    for (int i = 0; i < NBLK; i += 4) {
        gs0 += pp[i].y     * expf(pp[i].x - gm);
        gs1 += pp[i + 1].y * expf(pp[i + 1].x - gm);
        gs2 += pp[i + 2].y * expf(pp[i + 2].x - gm);
        gs3 += pp[i + 3].y * expf(pp[i + 3].x - gm);
    }
    float inv = 1.0f / ((gs0 + gs1) + (gs2 + gs3));

    float4* p = (float4*)(out + (size_t)row * CELLS) + half * 1024;
#pragma unroll
    for (int i = 0; i < 4; ++i) {
        float4 v = p[t + i * 256];
        v.x = expf(v.x - gm) * inv;
        v.y = expf(v.y - gm) * inv;
        v.z = expf(v.z - gm) * inv;
        v.w = expf(v.w - gm) * inv;
        p[t + i * 256] = v;
    }
}

// ---------------------------------------------------------------------------
extern "C" void kernel_launch(void* const* d_in, const int* in_sizes, int n_in,
                              void* d_out, int out_size, void* d_ws, size_t ws_size,
                              hipStream_t stream) {
    (void)in_sizes; (void)n_in; (void)out_size; (void)ws_size;
    const float* memory = (const float*)d_in[0];
    const float* keys   = (const float*)d_in[1];
    const float* betas  = (const float*)d_in[2];
    const float* mask   = (const float*)d_in[3];
    float* out = (float*)d_out;
    float* ws  = (float*)d_ws;

    ca_prep<<<B * H, 256, 0, stream>>>(keys, mask, ws);
    dim3 g1(NBLK, B);
    ca_scores<<<g1, 256, 0, stream>>>((const float4*)memory, ws, betas, out,
                                      ws + OFF_PART);
    ca_norm<<<2 * B * H, 256, 0, stream>>>(out, ws + OFF_PART);
}

// Round 4
// 40.326 us; speedup vs baseline: 1.3964x; 1.2515x over previous
//
#include <hip/hip_runtime.h>
#include <cstdint>
#include <cmath>

#define EPS_F 1e-8f

constexpr int B = 8, H = 8, CELLS = 8192, W = 256;
constexpr int W4 = 64;              // float4 per W-row
constexpr int TC = 64;              // cells per block in kernel1
constexpr int NBLK = CELLS / TC;    // 128 score-blocks per (b,h) row

// ws layout (floats):
//   [0, 32768)        kqm2 [B][W4][16 float4]: f4 0..7 = kq4[h], 8..15 = m2_4[h]
//   [32768, 32832)    kn   [B][H]
//   [32832, +16384)   part [B][H][NBLK][2]  (block max, block sumexp)
constexpr size_t OFF_KN   = 32768;
constexpr size_t OFF_PART = 32832;

// ---------------------------------------------------------------------------
// Kernel 0: per (b,h): kq = k*m^2, m2 = m^2 (per-w4 interleaved), kn = ||k*m||
// ---------------------------------------------------------------------------
__global__ __launch_bounds__(256) void ca_prep(
    const float* __restrict__ keys, const float* __restrict__ mask,
    float* __restrict__ ws)
{
    const int bh = blockIdx.x;        // b*8 + h
    const int b = bh >> 3, h = bh & 7;
    const int t = threadIdx.x;        // w
    float k = keys[bh * W + t];
    float m = mask[bh * W + t];       // MASK_MIN = 0 -> mask unchanged
    float m2 = m * m;
    const int w4 = t >> 2, e = t & 3;
    ws[(((size_t)b * W4 + w4) * 16 + h) * 4 + e]     = k * m2;
    ws[(((size_t)b * W4 + w4) * 16 + 8 + h) * 4 + e] = m2;

    float km = k * m;
    float v = km * km;
#pragma unroll
    for (int s = 32; s; s >>= 1) v += __shfl_xor(v, s, 64);
    __shared__ float red[4];
    const int lane = t & 63, wv = t >> 6;
    if (lane == 0) red[wv] = v;
    __syncthreads();
    if (t == 0) ws[OFF_KN + bh] = sqrtf((red[0] + red[1]) + (red[2] + red[3]));
}

// ---------------------------------------------------------------------------
// Kernel 1: 64 cells/block, 512 threads (8 waves).
//  - stage 64KB tile: fully-coalesced global float4 loads -> LDS, row-XOR-swz
//  - wave wv computes W-eighth wv (wave-uniform kq/m2 -> s_load), lane = cell
//  - cross-wave reduce through reused LDS; wave wv finalizes head wv
// grid = (NBLK, B) = (128, 8)
// ---------------------------------------------------------------------------
__global__ __launch_bounds__(512, 4) void ca_scores(
    const float4* __restrict__ mem4,   // [B*CELLS][W4]
    const float* __restrict__ ws,
    const float* __restrict__ betas,   // [B*H]
    float* __restrict__ out,           // [B*H][CELLS]
    float* __restrict__ part)
{
    __shared__ float4 s_mem[TC * W4];          // 64 KB
    float* s_red = (float*)s_mem;              // reuse as [8][64][4] float4

    const int b = blockIdx.y, blk = blockIdx.x;
    const int t = threadIdx.x;
    const int lane = t & 63;
    const int wvu = __builtin_amdgcn_readfirstlane(t >> 6);  // 0..7
    const int c0 = blk * TC;

    // ---- stage: lane-contiguous global loads (1KB/row/instr), swizzled LDS ----
    const float4* __restrict__ gbase = mem4 + ((size_t)b * CELLS + c0) * W4;
#pragma unroll
    for (int i = 0; i < 8; ++i) {
        int g   = t + i * 512;                 // f4 id in 64x64 tile
        int row = g >> 6, s = g & 63;          // row uniform per (wave,i)
        s_mem[row * W4 + (s ^ (row & 7))] = gbase[g];
    }
    __syncthreads();

    // ---- compute: wave wvu owns f4 slice [wvu*8, wvu*8+8); lane = cell ----
    const float4* __restrict__ kb = (const float4*)ws + (size_t)b * W4 * 16;
    const int cell = lane;
    const int csw  = cell & 7;
    const float4* __restrict__ mrow = s_mem + cell * W4;

    float dot[H], nr[H];
#pragma unroll
    for (int h = 0; h < H; ++h) { dot[h] = 0.f; nr[h] = 0.f; }

#pragma unroll
    for (int jj = 0; jj < 8; ++jj) {
        const int j = wvu * 8 + jj;
        float4 a = mrow[j ^ csw];              // swizzled read -> banks spread
        const float4* __restrict__ kk = kb + j * 16;   // wave-uniform -> s_load
        float4 sq = make_float4(a.x * a.x, a.y * a.y, a.z * a.z, a.w * a.w);
#pragma unroll
        for (int h = 0; h < H; ++h) {
            float4 kq = kk[h];
            float4 q  = kk[8 + h];
            dot[h] = fmaf(a.w, kq.w, fmaf(a.z, kq.z, fmaf(a.y, kq.y, fmaf(a.x, kq.x, dot[h]))));
            nr[h]  = fmaf(sq.w, q.w,  fmaf(sq.z, q.z,  fmaf(sq.y, q.y,  fmaf(sq.x, q.x,  nr[h]))));
        }
    }
    __syncthreads();   // all s_mem reads done; safe to overwrite with partials

    // ---- write partials: [wv][cell][q^(cell&3)] float4 ----
    {
        float4* rq = (float4*)s_red + ((size_t)wvu * 64 + cell) * 4;
        const int q0 = cell & 3;
        rq[0 ^ q0] = make_float4(dot[0], dot[1], dot[2], dot[3]);
        rq[1 ^ q0] = make_float4(dot[4], dot[5], dot[6], dot[7]);
        rq[2 ^ q0] = make_float4(nr[0], nr[1], nr[2], nr[3]);
        rq[3 ^ q0] = make_float4(nr[4], nr[5], nr[6], nr[7]);
    }
    __syncthreads();

    // ---- reduce: wave wvu owns head h=wvu, lane = cell ----
    const int qd = wvu >> 2, e = wvu & 3;
    float d = 0.f, n = 0.f;
#pragma unroll
    for (int w = 0; w < 8; ++w) {
        const float* base = s_red + ((size_t)w * 64 + lane) * 16;
        d += base[((qd ^ (lane & 3)) << 2) + e];
        n += base[(((2 + qd) ^ (lane & 3)) << 2) + e];
    }

    const float kn = ws[OFF_KN + b * H + wvu];   // wave-uniform
    const float be = betas[b * H + wvu];         // wave-uniform
    float s0 = d * be / (kn * sqrtf(n) + EPS_F);
    out[((size_t)(b * H + wvu)) * CELLS + c0 + lane] = s0;

    // ---- softmax partials: wave-local butterfly over the 64 cells ----
    float m0 = s0;
#pragma unroll
    for (int s = 32; s; s >>= 1) m0 = fmaxf(m0, __shfl_xor(m0, s, 64));
    float e0 = expf(s0 - m0);
#pragma unroll
    for (int s = 32; s; s >>= 1) e0 += __shfl_xor(e0, s, 64);
    if (lane == 0) {
        size_t pi = (((size_t)(b * H + wvu)) * NBLK + blk) * 2;
        part[pi] = m0; part[pi + 1] = e0;
    }
}

// ---------------------------------------------------------------------------
// Kernel 2: combine 128 partials per row via lane-parallel butterfly, then
// normalize. grid = 128 blocks (2 per row), block = 256.
// ---------------------------------------------------------------------------
__global__ __launch_bounds__(256) void ca_norm(
    float* __restrict__ out, const float* __restrict__ part)
{
    const int row  = blockIdx.x >> 1;   // 0..63 = b*H + h
    const int half = blockIdx.x & 1;
    const int t = threadIdx.x, lane = t & 63;

    const float2* __restrict__ pp = (const float2*)(part + (size_t)row * (NBLK * 2));
    float2 p0 = pp[lane], p1 = pp[64 + lane];
    float gm = fmaxf(p0.x, p1.x);
#pragma unroll
    for (int s = 32; s; s >>= 1) gm = fmaxf(gm, __shfl_xor(gm, s, 64));
    float gs = p0.y * expf(p0.x - gm) + p1.y * expf(p1.x - gm);
#pragma unroll
    for (int s = 32; s; s >>= 1) gs += __shfl_xor(gs, s, 64);
    float inv = 1.0f / gs;

    float4* p = (float4*)(out + (size_t)row * CELLS) + half * 1024;
#pragma unroll
    for (int i = 0; i < 4; ++i) {
        float4 v = p[t + i * 256];
        v.x = expf(v.x - gm) * inv;
        v.y = expf(v.y - gm) * inv;
        v.z = expf(v.z - gm) * inv;
        v.w = expf(v.w - gm) * inv;
        p[t + i * 256] = v;
    }
}

// ---------------------------------------------------------------------------
extern "C" void kernel_launch(void* const* d_in, const int* in_sizes, int n_in,
                              void* d_out, int out_size, void* d_ws, size_t ws_size,
                              hipStream_t stream) {
    (void)in_sizes; (void)n_in; (void)out_size; (void)ws_size;
    const float* memory = (const float*)d_in[0];
    const float* keys   = (const float*)d_in[1];
    const float* betas  = (const float*)d_in[2];
    const float* mask   = (const float*)d_in[3];
    float* out = (float*)d_out;
    float* ws  = (float*)d_ws;

    ca_prep<<<B * H, 256, 0, stream>>>(keys, mask, ws);
    dim3 g1(NBLK, B);
    ca_scores<<<g1, 512, 0, stream>>>((const float4*)memory, ws, betas, out,
                                      ws + OFF_PART);
    ca_norm<<<2 * B * H, 256, 0, stream>>>(out, ws + OFF_PART);
}

// Round 5
// 28.267 us; speedup vs baseline: 1.9921x; 1.4266x over previous
//
#include <hip/hip_runtime.h>
#include <cstdint>
#include <cmath>

#define EPS_F 1e-8f

constexpr int B = 8, H = 8, CELLS = 8192, W = 256;
constexpr int W4 = 64;             // float4 per W-row
constexpr int TC = 32;             // cells per block
constexpr int NBLK = CELLS / TC;   // 256 blocks per (b,h) row
constexpr int PAD = 65;            // padded f4 stride (bank spread)

// ---------------------------------------------------------------------------
// Kernel A: fused prep + scores + softmax partials.
// grid = (NBLK, B) = (256, 8) = 2048 blocks, 256 threads, 3 blocks/CU.
// Lane layout in compute: lane = (cell_sub<<3) | head; each lane computes the
// COMPLETE dot+norm for its (cell, head) -> no reduction, no s_load pressure.
// ---------------------------------------------------------------------------
__global__ __launch_bounds__(256, 3) void ca_scores(
    const float4* __restrict__ mem4,   // [B*CELLS][W4]
    const float* __restrict__ keys,    // [B*H*W]
    const float* __restrict__ mask,    // [B*H*W]
    const float* __restrict__ betas,   // [B*H]
    float* __restrict__ out,           // [B*H][CELLS]
    float2* __restrict__ part)         // [B*H][NBLK] (max, sumexp)
{
    __shared__ float4 s_tile[TC * PAD];   // 33,280 B  memory tile (padded rows)
    __shared__ float4 s_kq[H * PAD];      //  8,320 B  k*m^2 per head (padded)
    __shared__ float4 s_m2[H * PAD];      //  8,320 B  m^2 per head (padded)
    __shared__ float  s_kn[H];
    __shared__ float  s_fin[4 * H];       // per-wave max partials
    __shared__ float  s_sum[4 * H];       // per-wave sum partials
    __shared__ float  s_sc[H][TC + 1];    // score transpose buffer

    const int b = blockIdx.y, blk = blockIdx.x, t = threadIdx.x;
    const int c0 = blk * TC;
    const int lane = t & 63, wv = t >> 6;

    // ---- prep loads FIRST (L2-resident; complete before stage loads) ----
    const int ph = t >> 5;               // head 0..7 (32 threads each)
    const int pw = t & 31;               // f4 slot 0..31 (and +32)
    const float4* __restrict__ kb4 = (const float4*)(keys + ((size_t)b * H + ph) * W);
    const float4* __restrict__ mb4 = (const float4*)(mask + ((size_t)b * H + ph) * W);
    float4 k0 = kb4[pw], k1 = kb4[pw + 32];
    float4 m0 = mb4[pw], m1 = mb4[pw + 32];

    // ---- stage loads (HBM burst, stays in flight during prep compute) ----
    const float4* __restrict__ gbase = mem4 + ((size_t)b * CELLS + c0) * W4;
    float4 st[8];
#pragma unroll
    for (int i = 0; i < 8; ++i) st[i] = gbase[t + i * 256];

    // ---- prep compute -> LDS (MASK_MIN = 0 -> mask unchanged) ----
    float4 q0 = make_float4(m0.x * m0.x, m0.y * m0.y, m0.z * m0.z, m0.w * m0.w);
    float4 q1 = make_float4(m1.x * m1.x, m1.y * m1.y, m1.z * m1.z, m1.w * m1.w);
    float4 kq0 = make_float4(k0.x * q0.x, k0.y * q0.y, k0.z * q0.z, k0.w * q0.w);
    float4 kq1 = make_float4(k1.x * q1.x, k1.y * q1.y, k1.z * q1.z, k1.w * q1.w);
    s_kq[ph * PAD + pw]      = kq0;
    s_kq[ph * PAD + pw + 32] = kq1;
    s_m2[ph * PAD + pw]      = q0;
    s_m2[ph * PAD + pw + 32] = q1;
    // keys_norm^2 partial: sum of (k*m)^2 over this thread's 8 w
    float km;
    float v = 0.f;
    km = k0.x * m0.x; v = fmaf(km, km, v);
    km = k0.y * m0.y; v = fmaf(km, km, v);
    km = k0.z * m0.z; v = fmaf(km, km, v);
    km = k0.w * m0.w; v = fmaf(km, km, v);
    km = k1.x * m1.x; v = fmaf(km, km, v);
    km = k1.y * m1.y; v = fmaf(km, km, v);
    km = k1.z * m1.z; v = fmaf(km, km, v);
    km = k1.w * m1.w; v = fmaf(km, km, v);
#pragma unroll
    for (int s = 1; s < 32; s <<= 1) v += __shfl_xor(v, s, 64);  // over 32-group
    if ((t & 31) == 0) s_kn[ph] = sqrtf(v);

    // ---- stage ds_writes (compiler waits vmcnt for st[] here) ----
#pragma unroll
    for (int i = 0; i < 8; ++i) {
        int g = t + i * 256;
        s_tile[(g >> 6) * PAD + (g & 63)] = st[i];
    }
    __syncthreads();

    // ---- compute: lane = (cs, h); full dot+norm per lane ----
    const int h  = lane & 7;
    const int cs = lane >> 3;            // 0..7
    const int c  = wv * 8 + cs;          // 0..31
    const float4* __restrict__ pa = s_tile + c * PAD;
    const float4* __restrict__ pk = s_kq + h * PAD;
    const float4* __restrict__ pq = s_m2 + h * PAD;

    float4 dt = make_float4(0.f, 0.f, 0.f, 0.f);
    float4 nr = make_float4(0.f, 0.f, 0.f, 0.f);
#pragma unroll 8
    for (int w = 0; w < W4; ++w) {
        float4 a  = pa[w];               // 8 distinct addrs, banks spread, bcast
        float4 kq = pk[w];
        float4 q  = pq[w];
        dt.x = fmaf(a.x, kq.x, dt.x);
        dt.y = fmaf(a.y, kq.y, dt.y);
        dt.z = fmaf(a.z, kq.z, dt.z);
        dt.w = fmaf(a.w, kq.w, dt.w);
        nr.x = fmaf(a.x * a.x, q.x, nr.x);
        nr.y = fmaf(a.y * a.y, q.y, nr.y);
        nr.z = fmaf(a.z * a.z, q.z, nr.z);
        nr.w = fmaf(a.w * a.w, q.w, nr.w);
    }
    float d = (dt.x + dt.y) + (dt.z + dt.w);
    float n = (nr.x + nr.y) + (nr.z + nr.w);

    float kn = s_kn[h];
    float be = betas[b * H + h];
    float score = d * be / (kn * sqrtf(n) + EPS_F);
    s_sc[h][c] = score;

    // per-wave max over the 8 cells (xor 8/16/32 mixes cs only, keeps h)
    float mx = score;
#pragma unroll
    for (int s = 8; s < 64; s <<= 1) mx = fmaxf(mx, __shfl_xor(mx, s, 64));
    if (lane < 8) s_fin[wv * 8 + lane] = mx;
    __syncthreads();

    // coalesced score store (32 consecutive floats per head row)
    {
        const int oh = t >> 5, oc = t & 31;
        out[((size_t)(b * H + oh)) * CELLS + c0 + oc] = s_sc[oh][oc];
    }
    float gm = fmaxf(fmaxf(s_fin[h], s_fin[8 + h]),
                     fmaxf(s_fin[16 + h], s_fin[24 + h]));
    float e = expf(score - gm);
#pragma unroll
    for (int s = 8; s < 64; s <<= 1) e += __shfl_xor(e, s, 64);
    if (lane < 8) s_sum[wv * 8 + lane] = e;
    __syncthreads();
    if (t < 8) {
        float s4 = (s_sum[t] + s_sum[8 + t]) + (s_sum[16 + t] + s_sum[24 + t]);
        part[((size_t)(b * H + t)) * NBLK + blk] = make_float2(gm, s4);
    }
}

// ---------------------------------------------------------------------------
// Kernel B: combine 256 partials per row (butterfly) + normalize.
// grid = 512 (8 per row), 256 threads, 1 float4 per thread.
// ---------------------------------------------------------------------------
__global__ __launch_bounds__(256) void ca_norm(
    float* __restrict__ out, const float2* __restrict__ part)
{
    const int row = blockIdx.x >> 3;     // b*H + h
    const int seg = blockIdx.x & 7;
    const int t = threadIdx.x, lane = t & 63;

    const float2* __restrict__ pp = part + (size_t)row * NBLK;
    float2 a0 = pp[lane], a1 = pp[lane + 64], a2 = pp[lane + 128], a3 = pp[lane + 192];
    float gm = fmaxf(fmaxf(a0.x, a1.x), fmaxf(a2.x, a3.x));
#pragma unroll
    for (int s = 32; s; s >>= 1) gm = fmaxf(gm, __shfl_xor(gm, s, 64));
    float gs = a0.y * expf(a0.x - gm) + a1.y * expf(a1.x - gm)
             + a2.y * expf(a2.x - gm) + a3.y * expf(a3.x - gm);
#pragma unroll
    for (int s = 32; s; s >>= 1) gs += __shfl_xor(gs, s, 64);
    float inv = 1.0f / gs;

    float4* p = (float4*)(out + (size_t)row * CELLS) + seg * 256;
    float4 vv = p[t];
    vv.x = expf(vv.x - gm) * inv;
    vv.y = expf(vv.y - gm) * inv;
    vv.z = expf(vv.z - gm) * inv;
    vv.w = expf(vv.w - gm) * inv;
    p[t] = vv;
}

// ---------------------------------------------------------------------------
extern "C" void kernel_launch(void* const* d_in, const int* in_sizes, int n_in,
                              void* d_out, int out_size, void* d_ws, size_t ws_size,
                              hipStream_t stream) {
    (void)in_sizes; (void)n_in; (void)out_size; (void)ws_size;
    const float* memory = (const float*)d_in[0];
    const float* keys   = (const float*)d_in[1];
    const float* betas  = (const float*)d_in[2];
    const float* mask   = (const float*)d_in[3];
    float* out = (float*)d_out;
    float2* part = (float2*)d_ws;

    dim3 gA(NBLK, B);
    ca_scores<<<gA, 256, 0, stream>>>((const float4*)memory, keys, mask, betas,
                                      out, part);
    ca_norm<<<8 * B * H, 256, 0, stream>>>(out, part);
}